// Round 1
// baseline (350.799 us; speedup 1.0000x reference)
//
#include <hip/hip_runtime.h>

// ---------------------------------------------------------------------------
// WaveSubsystem: out = tanh(c@W_mod + b_mod) * (a_diag*w + (w@A_V)@A_U^T)
//                      + [c z]@W_B + b_B
// B=4096, D_W=2048, D_C=1024, D_P=2048, RANK=512.  All inputs f32, out f32.
// Strategy: bf16 MFMA (16x16x32), m97-style 128x128x32 tiles with
// global_load_lds width=16 staging. Pre-pass converts inputs to bf16 and
// transposes the B-operands into [N][K] layout so B-fragments are
// contiguous-k ds_read_b128.
// ---------------------------------------------------------------------------

#define DEV __device__ __forceinline__

typedef __bf16 v8bf __attribute__((ext_vector_type(8)));
typedef __bf16 v4bf __attribute__((ext_vector_type(4)));
typedef float  v4f  __attribute__((ext_vector_type(4)));

typedef __attribute__((address_space(1))) const unsigned int* as1_cuint_ptr;
typedef __attribute__((address_space(3))) unsigned int*       as3_uint_ptr;

DEV void async16(const void* g, void* l) {
  __builtin_amdgcn_global_load_lds(
      (as1_cuint_ptr)(unsigned long long)g,
      (as3_uint_ptr)(unsigned long long)l,
      16, 0, 0);
}

DEV float tanh_fast(float x) {
  x = fminf(15.f, fmaxf(-15.f, x));
  float e = __expf(2.f * x);
  return (e - 1.f) / (e + 1.f);
}

// --------------------------- convert kernels -------------------------------

__global__ void cvt_f32_bf16(const float* __restrict__ src,
                             __bf16* __restrict__ dst, int n) {
  int i = (blockIdx.x * 256 + threadIdx.x) * 4;
  if (i + 3 < n) {
    float4 v = *reinterpret_cast<const float4*>(src + i);
    v4bf o;
    o.x = (__bf16)v.x; o.y = (__bf16)v.y; o.z = (__bf16)v.z; o.w = (__bf16)v.w;
    *reinterpret_cast<v4bf*>(dst + i) = o;
  }
}

// src [R][C] f32 -> dst [C][R] bf16  (B^T layout producer)
__global__ void transpose_cvt(const float* __restrict__ src,
                              __bf16* __restrict__ dst, int R, int C) {
  __shared__ float t[32][33];
  const int c0 = blockIdx.x * 32, r0 = blockIdx.y * 32;
  const int tx = threadIdx.x & 31, ty = threadIdx.x >> 5;  // ty in 0..7
#pragma unroll
  for (int rr = 0; rr < 32; rr += 8)
    t[ty + rr][tx] = src[(size_t)(r0 + ty + rr) * C + c0 + tx];
  __syncthreads();
#pragma unroll
  for (int rr = 0; rr < 32; rr += 8)
    dst[(size_t)(c0 + ty + rr) * R + r0 + tx] = (__bf16)t[tx][ty + rr];
}

__global__ void adiag_kernel(const float* __restrict__ A_diag,
                             float* __restrict__ out, int n) {
  int i = blockIdx.x * 256 + threadIdx.x;
  if (i < n) out[i] = tanh_fast(A_diag[i]) * 0.9f;
}

// ------------------------------ GEMM ---------------------------------------
// C[M,N] = A[M,K] @ Bt[N,K]^T, bf16 inputs, f32 accumulate.
// MODE 0: store bf16.  MODE 1: store bf16 tanh(acc + bias[n]).
// MODE 2: store f32 out = mod*(adiag[n]*wprev + alr) + acc + bias[n].
// SPLIT: A comes from A0 (lda0) for k<kswitch else A1 (lda1, col k-kswitch).
template <int MODE, bool SPLIT>
__global__ __launch_bounds__(256, 2) void gemm_bf16_k(
    const __bf16* __restrict__ A0, int lda0, int kswitch,
    const __bf16* __restrict__ A1, int lda1,
    const __bf16* __restrict__ Bt, int ldb,
    int M, int N, int K,
    void* __restrict__ outp,
    const float* __restrict__ bias,
    const __bf16* __restrict__ modp,
    const __bf16* __restrict__ alrp,
    const float* __restrict__ wprev,
    const float* __restrict__ adiag) {
  __shared__ __align__(16) __bf16 As[128 * 32];  // [m][k] row-major, 8KB
  __shared__ __align__(16) __bf16 Bs[128 * 32];  // [n][k] row-major, 8KB

  const int tid  = threadIdx.x;
  const int lane = tid & 63;
  const int wid  = tid >> 6;       // 4 waves: 2x2 of 64x64
  const int wm   = wid >> 1;
  const int wn   = wid & 1;
  const int l16  = lane & 15;
  const int quad = lane >> 4;

  const int m0 = blockIdx.y * 128;
  const int n0 = blockIdx.x * 128;

  const int sg_row = lane >> 2;        // 0..15 rows within a 1KB chunk
  const int sg_k   = (lane & 3) * 8;   // 0,8,16,24

  v4f acc[4][4];
#pragma unroll
  for (int i = 0; i < 4; ++i)
#pragma unroll
    for (int j = 0; j < 4; ++j) {
      v4f z = {0.f, 0.f, 0.f, 0.f};
      acc[i][j] = z;
    }

  for (int k0 = 0; k0 < K; k0 += 32) {
    __syncthreads();  // previous iteration's ds_reads done before overwrite
#pragma unroll
    for (int t = 0; t < 2; ++t) {
      const int chunk = wid * 2 + t;          // 0..7, 16 rows each
      const int row   = chunk * 16 + sg_row;  // 0..127
      const __bf16* gA;
      if (!SPLIT || k0 < kswitch)
        gA = A0 + (size_t)(m0 + row) * lda0 + (k0 + sg_k);
      else
        gA = A1 + (size_t)(m0 + row) * lda1 + (k0 - kswitch + sg_k);
      async16((const void*)gA, (void*)&As[chunk * 512 + lane * 8]);
      const __bf16* gB = Bt + (size_t)(n0 + row) * ldb + (k0 + sg_k);
      async16((const void*)gB, (void*)&Bs[chunk * 512 + lane * 8]);
    }
    __syncthreads();  // compiler drains vmcnt before barrier

    const v8bf* Ap = reinterpret_cast<const v8bf*>(As);
    const v8bf* Bp = reinterpret_cast<const v8bf*>(Bs);
    v8bf a[4], b[4];
#pragma unroll
    for (int i = 0; i < 4; ++i) a[i] = Ap[(wm * 64 + i * 16 + l16) * 4 + quad];
#pragma unroll
    for (int j = 0; j < 4; ++j) b[j] = Bp[(wn * 64 + j * 16 + l16) * 4 + quad];
#pragma unroll
    for (int i = 0; i < 4; ++i)
#pragma unroll
      for (int j = 0; j < 4; ++j)
        acc[i][j] = __builtin_amdgcn_mfma_f32_16x16x32_bf16(a[i], b[j],
                                                            acc[i][j], 0, 0, 0);
  }

  // Epilogue. C/D layout: col = lane&15 (n), row = quad*4 + reg (m).
  const int mBase = m0 + wm * 64 + quad * 4;
  const int nBase = n0 + wn * 64 + l16;

  if (MODE == 0) {
    __bf16* out = (__bf16*)outp;
#pragma unroll
    for (int j = 0; j < 4; ++j) {
      const int n = nBase + j * 16;
#pragma unroll
      for (int i = 0; i < 4; ++i)
#pragma unroll
        for (int r = 0; r < 4; ++r) {
          const int m = mBase + i * 16 + r;
          out[(size_t)m * N + n] = (__bf16)acc[i][j][r];
        }
    }
  } else if (MODE == 1) {
    __bf16* out = (__bf16*)outp;
#pragma unroll
    for (int j = 0; j < 4; ++j) {
      const int n  = nBase + j * 16;
      const float bn = bias[n];
#pragma unroll
      for (int i = 0; i < 4; ++i)
#pragma unroll
        for (int r = 0; r < 4; ++r) {
          const int m = mBase + i * 16 + r;
          out[(size_t)m * N + n] = (__bf16)tanh_fast(acc[i][j][r] + bn);
        }
    }
  } else {
    float* out = (float*)outp;
#pragma unroll
    for (int j = 0; j < 4; ++j) {
      const int n  = nBase + j * 16;
      const float bn = bias[n];
      const float ad = adiag[n];
#pragma unroll
      for (int i = 0; i < 4; ++i)
#pragma unroll
        for (int r = 0; r < 4; ++r) {
          const int m   = mBase + i * 16 + r;
          const size_t idx = (size_t)m * N + n;
          const float md = (float)modp[idx];
          const float al = (float)alrp[idx];
          out[idx] = md * (ad * wprev[idx] + al) + acc[i][j][r] + bn;
        }
    }
  }
}

// ------------------------------ launch -------------------------------------

extern "C" void kernel_launch(void* const* d_in, const int* in_sizes, int n_in,
                              void* d_out, int out_size, void* d_ws,
                              size_t ws_size, hipStream_t stream) {
  const float* w_prev = (const float*)d_in[0];
  const float* z_t    = (const float*)d_in[1];
  const float* c_t    = (const float*)d_in[2];
  const float* A_diag = (const float*)d_in[3];
  const float* A_U    = (const float*)d_in[4];
  const float* A_V    = (const float*)d_in[5];
  const float* W_mod  = (const float*)d_in[6];
  const float* b_mod  = (const float*)d_in[7];
  const float* W_B    = (const float*)d_in[8];
  const float* b_B    = (const float*)d_in[9];

  constexpr int Bsz = 4096, DW = 2048, DC = 1024, DP = 2048, RK = 512;
  const size_t MB = 1ull << 20;
  char* ws = (char*)d_ws;
  // workspace layout (80 MB + 8 KB):
  __bf16* w_bf   = (__bf16*)(ws + 0);        // 16 MB (reused by alr after P)
  __bf16* z_bf   = (__bf16*)(ws + 16 * MB);  // 16 MB
  __bf16* c_bf   = (__bf16*)(ws + 32 * MB);  //  8 MB
  __bf16* AU_bf  = (__bf16*)(ws + 40 * MB);  //  2 MB  [2048][512] == B^T
  __bf16* AVt    = (__bf16*)(ws + 42 * MB);  //  2 MB  [512][2048]
  __bf16* Wmodt  = (__bf16*)(ws + 44 * MB);  //  4 MB  [2048][1024]
  __bf16* WBt    = (__bf16*)(ws + 48 * MB);  // 12 MB  [2048][3072]
  __bf16* P_bf   = (__bf16*)(ws + 60 * MB);  //  4 MB  [4096][512]
  __bf16* mod_bf = (__bf16*)(ws + 64 * MB);  // 16 MB  [4096][2048]
  __bf16* alr_bf = (__bf16*)(ws + 0);        // 16 MB, reuses w_bf region
  float*  adiag  = (float*)(ws + 80 * MB);   //  8 KB

  cvt_f32_bf16<<<(Bsz * DW) / 1024, 256, 0, stream>>>(w_prev, w_bf, Bsz * DW);
  cvt_f32_bf16<<<(Bsz * DP) / 1024, 256, 0, stream>>>(z_t, z_bf, Bsz * DP);
  cvt_f32_bf16<<<(Bsz * DC) / 1024, 256, 0, stream>>>(c_t, c_bf, Bsz * DC);
  cvt_f32_bf16<<<(DW * RK) / 1024, 256, 0, stream>>>(A_U, AU_bf, DW * RK);
  transpose_cvt<<<dim3(RK / 32, DW / 32), 256, 0, stream>>>(A_V, AVt, DW, RK);
  transpose_cvt<<<dim3(DW / 32, DC / 32), 256, 0, stream>>>(W_mod, Wmodt, DC, DW);
  transpose_cvt<<<dim3(DW / 32, (DC + DP) / 32), 256, 0, stream>>>(W_B, WBt,
                                                                   DC + DP, DW);
  adiag_kernel<<<DW / 256, 256, 0, stream>>>(A_diag, adiag, DW);

  // P = w @ A_V : [4096, 512], K=2048
  gemm_bf16_k<0, false><<<dim3(RK / 128, Bsz / 128), 256, 0, stream>>>(
      w_bf, DW, 0, w_bf, DW, AVt, DW, Bsz, RK, DW, (void*)P_bf,
      nullptr, nullptr, nullptr, nullptr, nullptr);

  // mod = tanh(c @ W_mod + b_mod) : [4096, 2048], K=1024
  gemm_bf16_k<1, false><<<dim3(DW / 128, Bsz / 128), 256, 0, stream>>>(
      c_bf, DC, 0, c_bf, DC, Wmodt, DC, Bsz, DW, DC, (void*)mod_bf,
      b_mod, nullptr, nullptr, nullptr, nullptr);

  // alr = P @ A_U^T : [4096, 2048], K=512   (writes over w_bf region, safe:
  // stream-ordered after gemm_P consumed w_bf)
  gemm_bf16_k<0, false><<<dim3(DW / 128, Bsz / 128), 256, 0, stream>>>(
      P_bf, RK, 0, P_bf, RK, AU_bf, RK, Bsz, DW, RK, (void*)alr_bf,
      nullptr, nullptr, nullptr, nullptr, nullptr);

  // out = mod*(adiag*w_prev + alr) + [c z]@W_B + b_B : [4096, 2048], K=3072
  gemm_bf16_k<2, true><<<dim3(DW / 128, Bsz / 128), 256, 0, stream>>>(
      c_bf, DC, DC, z_bf, DP, WBt, DC + DP, Bsz, DW, DC + DP, d_out,
      b_B, mod_bf, alr_bf, w_prev, adiag);
}

// Round 2
// 333.973 us; speedup vs baseline: 1.0504x; 1.0504x over previous
//
#include <hip/hip_runtime.h>

// ---------------------------------------------------------------------------
// WaveSubsystem fused:
//   out = tanh(c@W_mod + b_mod) * (w @ M) + [c z]@W_B + b_B
// where M = diag(tanh(A_diag)*0.9) + A_V@A_U^T  (so w@M == a_diag*w + (w@A_V)@A_U^T)
// M^T (B^T layout for the GEMM) = diag(a) + A_U@A_V^T  -> one tiny GEMM.
// One fused main kernel: 3 accumulation phases over one output tile,
// single accumulator, mod held in registers, zero intermediate HBM traffic.
// ---------------------------------------------------------------------------

#define DEV __device__ __forceinline__

typedef __bf16 v8bf __attribute__((ext_vector_type(8)));
typedef __bf16 v4bf __attribute__((ext_vector_type(4)));
typedef float  v4f  __attribute__((ext_vector_type(4)));

typedef __attribute__((address_space(1))) const unsigned int* as1_cuint_ptr;
typedef __attribute__((address_space(3))) unsigned int*       as3_uint_ptr;

DEV void async16(const void* g, void* l) {
  __builtin_amdgcn_global_load_lds(
      (as1_cuint_ptr)(unsigned long long)g,
      (as3_uint_ptr)(unsigned long long)l,
      16, 0, 0);
}

DEV float tanh_fast(float x) {
  x = fminf(15.f, fmaxf(-15.f, x));
  float e = __expf(2.f * x);
  return (e - 1.f) / (e + 1.f);
}

// --------------------------- small kernels ---------------------------------

__global__ void cvt_f32_bf16(const float* __restrict__ src,
                             __bf16* __restrict__ dst, int n) {
  int i = (blockIdx.x * 256 + threadIdx.x) * 4;
  if (i + 3 < n) {
    float4 v = *reinterpret_cast<const float4*>(src + i);
    v4bf o;
    o.x = (__bf16)v.x; o.y = (__bf16)v.y; o.z = (__bf16)v.z; o.w = (__bf16)v.w;
    *reinterpret_cast<v4bf*>(dst + i) = o;
  }
}

// src [R][C] f32 -> dst [C][R] bf16  (B^T layout producer)
__global__ void transpose_cvt(const float* __restrict__ src,
                              __bf16* __restrict__ dst, int R, int C) {
  __shared__ float t[32][33];
  const int c0 = blockIdx.x * 32, r0 = blockIdx.y * 32;
  const int tx = threadIdx.x & 31, ty = threadIdx.x >> 5;
#pragma unroll
  for (int rr = 0; rr < 32; rr += 8)
    t[ty + rr][tx] = src[(size_t)(r0 + ty + rr) * C + c0 + tx];
  __syncthreads();
#pragma unroll
  for (int rr = 0; rr < 32; rr += 8)
    dst[(size_t)(c0 + ty + rr) * R + r0 + tx] = (__bf16)t[tx][ty + rr];
}

__global__ void adiag_kernel(const float* __restrict__ A_diag,
                             float* __restrict__ out, int n) {
  int i = blockIdx.x * 256 + threadIdx.x;
  if (i < n) out[i] = tanh_fast(A_diag[i]) * 0.9f;
}

// ---------------------- Mt builder GEMM ------------------------------------
// Mt[m][n'] = (A_U @ A_V^T)[m][n'] + (m==n' ? adiag[m] : 0), bf16 out.
// A = AU_bf [2048][512] row-major; Bt = AV_bf [2048][512] row-major.
__global__ __launch_bounds__(256, 2) void gemm_mt(
    const __bf16* __restrict__ A0, const __bf16* __restrict__ Bt,
    int N, int K, __bf16* __restrict__ out, const float* __restrict__ adiag) {
  __shared__ __align__(16) __bf16 As[128 * 32];
  __shared__ __align__(16) __bf16 Bs[128 * 32];

  const int tid = threadIdx.x, lane = tid & 63, wid = tid >> 6;
  const int wm = wid >> 1, wn = wid & 1, l16 = lane & 15, quad = lane >> 4;
  const int m0 = blockIdx.y * 128, n0 = blockIdx.x * 128;
  const int sg_row = lane >> 2, sg_k = (lane & 3) * 8;

  v4f acc[4][4];
#pragma unroll
  for (int i = 0; i < 4; ++i)
#pragma unroll
    for (int j = 0; j < 4; ++j) { v4f zz = {0,0,0,0}; acc[i][j] = zz; }

  for (int k0 = 0; k0 < K; k0 += 32) {
    __syncthreads();
#pragma unroll
    for (int t = 0; t < 2; ++t) {
      const int chunk = wid * 2 + t;
      const int row = chunk * 16 + sg_row;
      async16((const void*)(A0 + (size_t)(m0 + row) * K + k0 + sg_k),
              (void*)&As[chunk * 512 + lane * 8]);
      async16((const void*)(Bt + (size_t)(n0 + row) * K + k0 + sg_k),
              (void*)&Bs[chunk * 512 + lane * 8]);
    }
    __syncthreads();
    const v8bf* Ap = reinterpret_cast<const v8bf*>(As);
    const v8bf* Bp = reinterpret_cast<const v8bf*>(Bs);
    v8bf a[4], b[4];
#pragma unroll
    for (int i = 0; i < 4; ++i) a[i] = Ap[(wm * 64 + i * 16 + l16) * 4 + quad];
#pragma unroll
    for (int j = 0; j < 4; ++j) b[j] = Bp[(wn * 64 + j * 16 + l16) * 4 + quad];
#pragma unroll
    for (int i = 0; i < 4; ++i)
#pragma unroll
      for (int j = 0; j < 4; ++j)
        acc[i][j] = __builtin_amdgcn_mfma_f32_16x16x32_bf16(a[i], b[j],
                                                            acc[i][j], 0, 0, 0);
  }

  const int mBase = m0 + wm * 64 + quad * 4;
  const int nBase = n0 + wn * 64 + l16;
#pragma unroll
  for (int j = 0; j < 4; ++j) {
    const int n = nBase + j * 16;
#pragma unroll
    for (int i = 0; i < 4; ++i)
#pragma unroll
      for (int r = 0; r < 4; ++r) {
        const int m = mBase + i * 16 + r;
        float v = acc[i][j][r];
        if (m == n) v += adiag[m];
        out[(size_t)m * N + n] = (__bf16)v;
      }
  }
}

// ---------------------- fused main kernel ----------------------------------
// Per 128x128 output tile (m over batch, n over d_w):
//  phase A: acc = c@Wmodt        (K=1024) -> mod = tanh(acc+b_mod) in regs
//  phase B: acc = w@Mt           (K=2048) -> acc *= mod
//  phase C: acc += [c z]@WBt     (K=3072)
//  out = acc + b_B (f32)
__global__ __launch_bounds__(256, 2) void fused_main(
    const __bf16* __restrict__ c, const __bf16* __restrict__ z,
    const __bf16* __restrict__ w, const __bf16* __restrict__ Wmodt,
    const __bf16* __restrict__ Mt, const __bf16* __restrict__ WBt,
    const float* __restrict__ b_mod, const float* __restrict__ b_B,
    float* __restrict__ out) {
  constexpr int DC = 1024, DW = 2048, KB = 3072;
  __shared__ __align__(16) __bf16 As[128 * 32];
  __shared__ __align__(16) __bf16 Bs[128 * 32];

  const int tid = threadIdx.x, lane = tid & 63, wid = tid >> 6;
  const int wm = wid >> 1, wn = wid & 1, l16 = lane & 15, quad = lane >> 4;
  const int m0 = blockIdx.y * 128;  // batch
  const int n0 = blockIdx.x * 128;  // d_w
  const int sg_row = lane >> 2, sg_k = (lane & 3) * 8;
  const int ldsA = (wid * 2) * 512 + lane * 8;       // chunk t=0
  const int ldsA2 = (wid * 2 + 1) * 512 + lane * 8;  // chunk t=1
  const int rowA = (wid * 2) * 16 + sg_row;
  const int rowA2 = (wid * 2 + 1) * 16 + sg_row;

  v4f acc[4][4];
#pragma unroll
  for (int i = 0; i < 4; ++i)
#pragma unroll
    for (int j = 0; j < 4; ++j) { v4f zz = {0,0,0,0}; acc[i][j] = zz; }

  // one staged k-step: A rows from gA (lda), B rows from gB (ldb)
  auto kstep = [&](const __bf16* gA, size_t lda, const __bf16* gB, size_t ldb,
                   int kA, int kB) {
    __syncthreads();
    async16((const void*)(gA + (size_t)(m0 + rowA) * lda + kA + sg_k),
            (void*)&As[ldsA]);
    async16((const void*)(gB + (size_t)(n0 + rowA) * ldb + kB + sg_k),
            (void*)&Bs[ldsA]);
    async16((const void*)(gA + (size_t)(m0 + rowA2) * lda + kA + sg_k),
            (void*)&As[ldsA2]);
    async16((const void*)(gB + (size_t)(n0 + rowA2) * ldb + kB + sg_k),
            (void*)&Bs[ldsA2]);
    __syncthreads();
    const v8bf* Ap = reinterpret_cast<const v8bf*>(As);
    const v8bf* Bp = reinterpret_cast<const v8bf*>(Bs);
    v8bf a[4], b[4];
#pragma unroll
    for (int i = 0; i < 4; ++i) a[i] = Ap[(wm * 64 + i * 16 + l16) * 4 + quad];
#pragma unroll
    for (int j = 0; j < 4; ++j) b[j] = Bp[(wn * 64 + j * 16 + l16) * 4 + quad];
#pragma unroll
    for (int i = 0; i < 4; ++i)
#pragma unroll
      for (int j = 0; j < 4; ++j)
        acc[i][j] = __builtin_amdgcn_mfma_f32_16x16x32_bf16(a[i], b[j],
                                                            acc[i][j], 0, 0, 0);
  };

  const int nBase = n0 + wn * 64 + l16;

  // ---- phase A: mod = tanh(c @ Wmodt + b_mod) ----
  for (int k0 = 0; k0 < DC; k0 += 32) kstep(c, DC, Wmodt, DC, k0, k0);

  v4f mod_s[4][4];
#pragma unroll
  for (int j = 0; j < 4; ++j) {
    const float bn = b_mod[nBase + j * 16];
#pragma unroll
    for (int i = 0; i < 4; ++i) {
#pragma unroll
      for (int r = 0; r < 4; ++r)
        mod_s[i][j][r] = tanh_fast(acc[i][j][r] + bn);
      v4f zz = {0,0,0,0};
      acc[i][j] = zz;
    }
  }

  // ---- phase B: acc = w @ Mt ----
  for (int k0 = 0; k0 < DW; k0 += 32) kstep(w, DW, Mt, DW, k0, k0);

#pragma unroll
  for (int i = 0; i < 4; ++i)
#pragma unroll
    for (int j = 0; j < 4; ++j) acc[i][j] *= mod_s[i][j];

  // ---- phase C: acc += [c z] @ WBt ----
  for (int k0 = 0; k0 < DC; k0 += 32) kstep(c, DC, WBt, KB, k0, k0);
  for (int k0 = DC; k0 < KB; k0 += 32) kstep(z, DW, WBt, KB, k0 - DC, k0);

  // ---- epilogue ----
  const int mBase = m0 + wm * 64 + quad * 4;
#pragma unroll
  for (int j = 0; j < 4; ++j) {
    const int n = nBase + j * 16;
    const float bn = b_B[n];
#pragma unroll
    for (int i = 0; i < 4; ++i)
#pragma unroll
      for (int r = 0; r < 4; ++r) {
        const int m = mBase + i * 16 + r;
        out[(size_t)m * DW + n] = acc[i][j][r] + bn;
      }
  }
}

// ------------------------------ launch -------------------------------------

extern "C" void kernel_launch(void* const* d_in, const int* in_sizes, int n_in,
                              void* d_out, int out_size, void* d_ws,
                              size_t ws_size, hipStream_t stream) {
  const float* w_prev = (const float*)d_in[0];
  const float* z_t    = (const float*)d_in[1];
  const float* c_t    = (const float*)d_in[2];
  const float* A_diag = (const float*)d_in[3];
  const float* A_U    = (const float*)d_in[4];
  const float* A_V    = (const float*)d_in[5];
  const float* W_mod  = (const float*)d_in[6];
  const float* b_mod  = (const float*)d_in[7];
  const float* W_B    = (const float*)d_in[8];
  const float* b_B    = (const float*)d_in[9];

  constexpr int Bsz = 4096, DW = 2048, DC = 1024, DP = 2048, RK = 512;
  const size_t MB = 1ull << 20;
  char* ws = (char*)d_ws;
  __bf16* w_bf  = (__bf16*)(ws + 0);        // 16 MB
  __bf16* z_bf  = (__bf16*)(ws + 16 * MB);  // 16 MB
  __bf16* c_bf  = (__bf16*)(ws + 32 * MB);  //  8 MB
  __bf16* AU_bf = (__bf16*)(ws + 40 * MB);  //  2 MB  [2048][512]
  __bf16* AV_bf = (__bf16*)(ws + 42 * MB);  //  2 MB  [2048][512]
  __bf16* Wmodt = (__bf16*)(ws + 44 * MB);  //  4 MB  [2048][1024]
  __bf16* WBt   = (__bf16*)(ws + 48 * MB);  // 12 MB  [2048][3072]
  __bf16* Mt    = (__bf16*)(ws + 60 * MB);  //  8 MB  [2048][2048]
  float*  adiag = (float*)(ws + 68 * MB);   //  8 KB

  cvt_f32_bf16<<<(Bsz * DW) / 1024, 256, 0, stream>>>(w_prev, w_bf, Bsz * DW);
  cvt_f32_bf16<<<(Bsz * DP) / 1024, 256, 0, stream>>>(z_t, z_bf, Bsz * DP);
  cvt_f32_bf16<<<(Bsz * DC) / 1024, 256, 0, stream>>>(c_t, c_bf, Bsz * DC);
  cvt_f32_bf16<<<(DW * RK) / 1024, 256, 0, stream>>>(A_U, AU_bf, DW * RK);
  cvt_f32_bf16<<<(DW * RK) / 1024, 256, 0, stream>>>(A_V, AV_bf, DW * RK);
  transpose_cvt<<<dim3(DW / 32, DC / 32), 256, 0, stream>>>(W_mod, Wmodt, DC, DW);
  transpose_cvt<<<dim3(DW / 32, (DC + DP) / 32), 256, 0, stream>>>(W_B, WBt,
                                                                   DC + DP, DW);
  adiag_kernel<<<DW / 256, 256, 0, stream>>>(A_diag, adiag, DW);

  // Mt = A_U @ A_V^T + diag(adiag) : [2048][2048] bf16, K=512
  gemm_mt<<<dim3(DW / 128, DW / 128), 256, 0, stream>>>(AU_bf, AV_bf, DW, RK,
                                                        Mt, adiag);

  // fused main: out[4096][2048] f32
  fused_main<<<dim3(DW / 128, Bsz / 128), 256, 0, stream>>>(
      c_bf, z_bf, w_bf, Wmodt, Mt, WBt, b_mod, b_B, (float*)d_out);
}

// Round 3
// 314.332 us; speedup vs baseline: 1.1160x; 1.0625x over previous
//
#include <hip/hip_runtime.h>

// ---------------------------------------------------------------------------
// WaveSubsystem fused:
//   out = tanh(c@W_mod + b_mod) * (w @ M) + [c z]@W_B + b_B
//   M^T = diag(tanh(A_diag)*0.9) + A_U@A_V^T   (tiny GEMM, bf16)
// Round 3: XOR-swizzled LDS (kills the 8-way bank conflict on b128 fragment
// reads: store k-seg s^((row>>1)&3) at quad slot s by permuting the staging
// load's global k-offset; both swizzles fold to lane constants), prologue
// collapsed to 3 launches.
// ---------------------------------------------------------------------------

#define DEV __device__ __forceinline__

typedef __bf16 v8bf __attribute__((ext_vector_type(8)));
typedef __bf16 v4bf __attribute__((ext_vector_type(4)));
typedef float  v4f  __attribute__((ext_vector_type(4)));

typedef __attribute__((address_space(1))) const unsigned int* as1_cuint_ptr;
typedef __attribute__((address_space(3))) unsigned int*       as3_uint_ptr;

DEV void async16(const void* g, void* l) {
  __builtin_amdgcn_global_load_lds(
      (as1_cuint_ptr)(unsigned long long)g,
      (as3_uint_ptr)(unsigned long long)l,
      16, 0, 0);
}

DEV float tanh_fast(float x) {
  x = fminf(15.f, fmaxf(-15.f, x));
  float e = __expf(2.f * x);
  return (e - 1.f) / (e + 1.f);
}

// --------------------------- prologue kernels ------------------------------

// One launch converts w(8192 blk), z(8192), c(4096), A_U(1024), A_V(1024).
// Each block handles 1024 contiguous elements (4/thread, float4->bf16x4).
__global__ void cvt_all(const float* __restrict__ w, const float* __restrict__ z,
                        const float* __restrict__ c, const float* __restrict__ au,
                        const float* __restrict__ av,
                        __bf16* __restrict__ wb, __bf16* __restrict__ zb,
                        __bf16* __restrict__ cb, __bf16* __restrict__ aub,
                        __bf16* __restrict__ avb) {
  int b = blockIdx.x;
  const float* src; __bf16* dst; int off;
  if (b < 8192)        { src = w;  dst = wb;  off = b; }
  else if (b < 16384)  { src = z;  dst = zb;  off = b - 8192; }
  else if (b < 20480)  { src = c;  dst = cb;  off = b - 16384; }
  else if (b < 21504)  { src = au; dst = aub; off = b - 20480; }
  else                 { src = av; dst = avb; off = b - 21504; }
  size_t i = (size_t)off * 1024 + (size_t)threadIdx.x * 4;
  float4 v = *reinterpret_cast<const float4*>(src + i);
  v4bf o;
  o.x = (__bf16)v.x; o.y = (__bf16)v.y; o.z = (__bf16)v.z; o.w = (__bf16)v.w;
  *reinterpret_cast<v4bf*>(dst + i) = o;
}

// One launch transposes W_mod [1024][2048] (2048 tiles) and W_B [3072][2048]
// (6144 tiles) into [C][R] bf16.
__global__ void transpose_both(const float* __restrict__ Wmod,
                               const float* __restrict__ WB,
                               __bf16* __restrict__ Wmodt,
                               __bf16* __restrict__ WBt) {
  __shared__ float t[32][33];
  int b = blockIdx.x;
  const float* src; __bf16* dst; int R;
  if (b < 2048) { src = Wmod; dst = Wmodt; R = 1024; }
  else          { b -= 2048; src = WB; dst = WBt; R = 3072; }
  const int c0 = (b & 63) * 32, r0 = (b >> 6) * 32;
  const int C = 2048;
  const int tx = threadIdx.x & 31, ty = threadIdx.x >> 5;
#pragma unroll
  for (int rr = 0; rr < 32; rr += 8)
    t[ty + rr][tx] = src[(size_t)(r0 + ty + rr) * C + c0 + tx];
  __syncthreads();
#pragma unroll
  for (int rr = 0; rr < 32; rr += 8)
    dst[(size_t)(c0 + ty + rr) * R + r0 + tx] = (__bf16)t[tx][ty + rr];
}

// ---------------------- Mt builder GEMM ------------------------------------
// Mt[m][n'] = (A_U @ A_V^T)[m][n'] + (m==n' ? tanh(A_diag[m])*0.9 : 0)
__global__ __launch_bounds__(256, 2) void gemm_mt(
    const __bf16* __restrict__ A0, const __bf16* __restrict__ Bt,
    int N, int K, __bf16* __restrict__ out, const float* __restrict__ A_diag) {
  __shared__ __align__(16) __bf16 As[128 * 32];
  __shared__ __align__(16) __bf16 Bs[128 * 32];

  const int tid = threadIdx.x, lane = tid & 63, wid = tid >> 6;
  const int wm = wid >> 1, wn = wid & 1, l16 = lane & 15, quad = lane >> 4;
  const int m0 = blockIdx.y * 128, n0 = blockIdx.x * 128;
  const int sg_row = lane >> 2;
  const int sk = ((lane & 3) ^ ((lane >> 3) & 3)) * 8;  // swizzled k-offset
  const int qs = quad ^ ((l16 >> 1) & 3);               // swizzled read slot

  v4f acc[4][4];
#pragma unroll
  for (int i = 0; i < 4; ++i)
#pragma unroll
    for (int j = 0; j < 4; ++j) { v4f zz = {0,0,0,0}; acc[i][j] = zz; }

  for (int k0 = 0; k0 < K; k0 += 32) {
    __syncthreads();
#pragma unroll
    for (int t = 0; t < 2; ++t) {
      const int chunk = wid * 2 + t;
      const int row = chunk * 16 + sg_row;
      async16((const void*)(A0 + (size_t)(m0 + row) * K + k0 + sk),
              (void*)&As[chunk * 512 + lane * 8]);
      async16((const void*)(Bt + (size_t)(n0 + row) * K + k0 + sk),
              (void*)&Bs[chunk * 512 + lane * 8]);
    }
    __syncthreads();
    const v8bf* Ap = reinterpret_cast<const v8bf*>(As);
    const v8bf* Bp = reinterpret_cast<const v8bf*>(Bs);
    v8bf a[4], b[4];
#pragma unroll
    for (int i = 0; i < 4; ++i) a[i] = Ap[(wm * 64 + i * 16 + l16) * 4 + qs];
#pragma unroll
    for (int j = 0; j < 4; ++j) b[j] = Bp[(wn * 64 + j * 16 + l16) * 4 + qs];
#pragma unroll
    for (int i = 0; i < 4; ++i)
#pragma unroll
      for (int j = 0; j < 4; ++j)
        acc[i][j] = __builtin_amdgcn_mfma_f32_16x16x32_bf16(a[i], b[j],
                                                            acc[i][j], 0, 0, 0);
  }

  const int mBase = m0 + wm * 64 + quad * 4;
  const int nBase = n0 + wn * 64 + l16;
#pragma unroll
  for (int j = 0; j < 4; ++j) {
    const int n = nBase + j * 16;
#pragma unroll
    for (int i = 0; i < 4; ++i)
#pragma unroll
      for (int r = 0; r < 4; ++r) {
        const int m = mBase + i * 16 + r;
        float v = acc[i][j][r];
        if (m == n) v += tanh_fast(A_diag[m]) * 0.9f;
        out[(size_t)m * N + n] = (__bf16)v;
      }
  }
}

// ---------------------- fused main kernel ----------------------------------
__global__ __launch_bounds__(256, 2) void fused_main(
    const __bf16* __restrict__ c, const __bf16* __restrict__ z,
    const __bf16* __restrict__ w, const __bf16* __restrict__ Wmodt,
    const __bf16* __restrict__ Mt, const __bf16* __restrict__ WBt,
    const float* __restrict__ b_mod, const float* __restrict__ b_B,
    float* __restrict__ out) {
  constexpr int DC = 1024, DW = 2048, KB = 3072;
  __shared__ __align__(16) __bf16 As[128 * 32];
  __shared__ __align__(16) __bf16 Bs[128 * 32];

  const int tid = threadIdx.x, lane = tid & 63, wid = tid >> 6;
  const int wm = wid >> 1, wn = wid & 1, l16 = lane & 15, quad = lane >> 4;
  const int m0 = blockIdx.y * 128;  // batch
  const int n0 = blockIdx.x * 128;  // d_w
  const int sg_row = lane >> 2;
  const int sk = ((lane & 3) ^ ((lane >> 3) & 3)) * 8;  // staging swizzle
  const int qs = quad ^ ((l16 >> 1) & 3);               // read swizzle
  const int ldsA  = (wid * 2) * 512 + lane * 8;
  const int ldsA2 = (wid * 2 + 1) * 512 + lane * 8;
  const int rowA  = (wid * 2) * 16 + sg_row;
  const int rowA2 = (wid * 2 + 1) * 16 + sg_row;

  v4f acc[4][4];
#pragma unroll
  for (int i = 0; i < 4; ++i)
#pragma unroll
    for (int j = 0; j < 4; ++j) { v4f zz = {0,0,0,0}; acc[i][j] = zz; }

  auto kstep = [&](const __bf16* gA, size_t lda, const __bf16* gB, size_t ldb,
                   int kA, int kB) {
    __syncthreads();
    async16((const void*)(gA + (size_t)(m0 + rowA) * lda + kA + sk),
            (void*)&As[ldsA]);
    async16((const void*)(gB + (size_t)(n0 + rowA) * ldb + kB + sk),
            (void*)&Bs[ldsA]);
    async16((const void*)(gA + (size_t)(m0 + rowA2) * lda + kA + sk),
            (void*)&As[ldsA2]);
    async16((const void*)(gB + (size_t)(n0 + rowA2) * ldb + kB + sk),
            (void*)&Bs[ldsA2]);
    __syncthreads();
    const v8bf* Ap = reinterpret_cast<const v8bf*>(As);
    const v8bf* Bp = reinterpret_cast<const v8bf*>(Bs);
    v8bf a[4], b[4];
#pragma unroll
    for (int i = 0; i < 4; ++i) a[i] = Ap[(wm * 64 + i * 16 + l16) * 4 + qs];
#pragma unroll
    for (int j = 0; j < 4; ++j) b[j] = Bp[(wn * 64 + j * 16 + l16) * 4 + qs];
#pragma unroll
    for (int i = 0; i < 4; ++i)
#pragma unroll
      for (int j = 0; j < 4; ++j)
        acc[i][j] = __builtin_amdgcn_mfma_f32_16x16x32_bf16(a[i], b[j],
                                                            acc[i][j], 0, 0, 0);
  };

  const int nBase = n0 + wn * 64 + l16;

  // ---- phase A: mod = tanh(c @ Wmodt + b_mod) ----
  for (int k0 = 0; k0 < DC; k0 += 32) kstep(c, DC, Wmodt, DC, k0, k0);

  v4f mod_s[4][4];
#pragma unroll
  for (int j = 0; j < 4; ++j) {
    const float bn = b_mod[nBase + j * 16];
#pragma unroll
    for (int i = 0; i < 4; ++i) {
#pragma unroll
      for (int r = 0; r < 4; ++r)
        mod_s[i][j][r] = tanh_fast(acc[i][j][r] + bn);
      v4f zz = {0,0,0,0};
      acc[i][j] = zz;
    }
  }

  // ---- phase B: acc = w @ Mt ----
  for (int k0 = 0; k0 < DW; k0 += 32) kstep(w, DW, Mt, DW, k0, k0);

#pragma unroll
  for (int i = 0; i < 4; ++i)
#pragma unroll
    for (int j = 0; j < 4; ++j) acc[i][j] *= mod_s[i][j];

  // ---- phase C: acc += [c z] @ WBt ----
  for (int k0 = 0; k0 < DC; k0 += 32) kstep(c, DC, WBt, KB, k0, k0);
  for (int k0 = DC; k0 < KB; k0 += 32) kstep(z, DW, WBt, KB, k0 - DC, k0);

  // ---- epilogue ----
  const int mBase = m0 + wm * 64 + quad * 4;
#pragma unroll
  for (int j = 0; j < 4; ++j) {
    const int n = nBase + j * 16;
    const float bn = b_B[n];
#pragma unroll
    for (int i = 0; i < 4; ++i)
#pragma unroll
      for (int r = 0; r < 4; ++r) {
        const int m = mBase + i * 16 + r;
        out[(size_t)m * DW + n] = acc[i][j][r] + bn;
      }
  }
}

// ------------------------------ launch -------------------------------------

extern "C" void kernel_launch(void* const* d_in, const int* in_sizes, int n_in,
                              void* d_out, int out_size, void* d_ws,
                              size_t ws_size, hipStream_t stream) {
  const float* w_prev = (const float*)d_in[0];
  const float* z_t    = (const float*)d_in[1];
  const float* c_t    = (const float*)d_in[2];
  const float* A_diag = (const float*)d_in[3];
  const float* A_U    = (const float*)d_in[4];
  const float* A_V    = (const float*)d_in[5];
  const float* W_mod  = (const float*)d_in[6];
  const float* b_mod  = (const float*)d_in[7];
  const float* W_B    = (const float*)d_in[8];
  const float* b_B    = (const float*)d_in[9];

  constexpr int Bsz = 4096, DW = 2048, RK = 512;
  const size_t MB = 1ull << 20;
  char* ws = (char*)d_ws;
  __bf16* w_bf  = (__bf16*)(ws + 0);        // 16 MB
  __bf16* z_bf  = (__bf16*)(ws + 16 * MB);  // 16 MB
  __bf16* c_bf  = (__bf16*)(ws + 32 * MB);  //  8 MB
  __bf16* AU_bf = (__bf16*)(ws + 40 * MB);  //  2 MB  [2048][512]
  __bf16* AV_bf = (__bf16*)(ws + 42 * MB);  //  2 MB  [2048][512]
  __bf16* Wmodt = (__bf16*)(ws + 44 * MB);  //  4 MB  [2048][1024]
  __bf16* WBt   = (__bf16*)(ws + 48 * MB);  // 12 MB  [2048][3072]
  __bf16* Mt    = (__bf16*)(ws + 60 * MB);  //  8 MB  [2048][2048]

  cvt_all<<<22528, 256, 0, stream>>>(w_prev, z_t, c_t, A_U, A_V,
                                     w_bf, z_bf, c_bf, AU_bf, AV_bf);
  transpose_both<<<2048 + 6144, 256, 0, stream>>>(W_mod, W_B, Wmodt, WBt);

  // Mt = A_U @ A_V^T + diag(tanh(A_diag)*0.9) : [2048][2048] bf16, K=512
  gemm_mt<<<dim3(DW / 128, DW / 128), 256, 0, stream>>>(AU_bf, AV_bf, DW, RK,
                                                        Mt, A_diag);

  // fused main: out[4096][2048] f32
  fused_main<<<dim3(DW / 128, Bsz / 128), 256, 0, stream>>>(
      c_bf, z_bf, w_bf, Wmodt, Mt, WBt, b_mod, b_B, (float*)d_out);
}